// Round 16
// baseline (41.827 us; speedup 1.0000x reference)
//
#include <hip/hip_runtime.h>
#include <math.h>

#define REFRACTORY 0.33f
#define FILT_WORDS 32768     // 128 KB LDS bitmap: 1,048,576 bits (exact, N<=2^20)
#define QWCAP 128            // per-WAVE queue entries (int2) -> 16 KB total
#define NWAVES 16            // 1024 threads / 64
#define DRAIN_THRESH 32      // R16: 32 active lanes per drain (was 16)

// ws layout: [0,4) flag (rec_mask byte-mode); [256, 256+4*N) acc
#define WS_ACC_OFF 256

typedef int v4i __attribute__((ext_vector_type(4)));

// ---------------------------------------------------------------------------
// Kernel 1 (setup): block 0 detects rec_mask storage mode (int32: dwords 0/1;
// packed bool bytes: dword view > 1); blocks 1.. init acc = 0.33*state + bias
// at output-neuron positions (the only acc slots ever read).
// ---------------------------------------------------------------------------
__global__ void setup(const unsigned int* __restrict__ rm, int nwords,
                      int* __restrict__ flag,
                      const int* __restrict__ out_ids,
                      const float* __restrict__ state,
                      const float* __restrict__ biases,
                      float* __restrict__ acc, int nout) {
    if (blockIdx.x == 0) {
        __shared__ int s;
        if (threadIdx.x == 0) s = 0;
        __syncthreads();
        int found = 0;
        for (int i = threadIdx.x; i < nwords; i += blockDim.x)
            if (rm[i] > 1u) found = 1;
        if (found) atomicOr(&s, 1);
        __syncthreads();
        if (threadIdx.x == 0) *flag = s;
    } else {
        int i = (blockIdx.x - 1) * blockDim.x + threadIdx.x;
        if (i < nout) {
            int n = out_ids[i];
            acc[n] = REFRACTORY * state[n] + biases[n];
        }
    }
}

// ---------------------------------------------------------------------------
// Full edge processing. Adds always land on the edge's TRUE dst; acc is only
// read at out_ids positions, so any extra add (shift>0 FPs) is invisible.
// ---------------------------------------------------------------------------
__device__ __forceinline__ void process_edge(
    int d, int e,
    const float* __restrict__ w, const int* __restrict__ src,
    const unsigned char* __restrict__ rmb, const int* __restrict__ input_idx,
    const float* __restrict__ state, const float* __restrict__ inp,
    float* __restrict__ acc, int bytemode) {
    int m = bytemode ? (int)rmb[e] : ((const int*)rmb)[e];
    float v = m ? REFRACTORY * state[src[e]] : inp[input_idx[e]];
    unsafeAtomicAdd(&acc[d], w[e] * v);
}

// ---------------------------------------------------------------------------
// Kernel 2 (fused): exact 128 KB LDS bitmap built in-block from out_ids.
// Stream dst (non-temporal: never re-read, keep L2/L3 for drain gathers)
// with branch-free probes into PER-WAVE queues; staggered per-wave drains
// (THRESH=32) overlap random hit traffic with other waves' streaming.
// One block per CU.
// ---------------------------------------------------------------------------
__global__ void __launch_bounds__(1024, 1)
edge_fused(const int* __restrict__ dst,
           const int* __restrict__ out_ids, int nout,
           int E, int shift,
           const float* __restrict__ w, const int* __restrict__ src,
           const unsigned char* __restrict__ rmb,
           const int* __restrict__ input_idx,
           const float* __restrict__ state, const float* __restrict__ inp,
           float* __restrict__ acc,
           const int* __restrict__ flag) {
    __shared__ unsigned int filt[FILT_WORDS];
    __shared__ int2 lq[NWAVES * QWCAP];
    __shared__ int wcnt[NWAVES];

    // zero bitmap
    {
        uint4* f4 = (uint4*)filt;
        uint4 z = make_uint4(0, 0, 0, 0);
        for (int i = threadIdx.x; i < FILT_WORDS / 4; i += blockDim.x)
            f4[i] = z;
    }
    if ((threadIdx.x & 63) == 0) wcnt[threadIdx.x >> 6] = 0;
    __syncthreads();
    // build exact membership bitmap from out_ids (L2-hot broadcast read)
    for (int i = threadIdx.x; i < nout; i += blockDim.x) {
        unsigned g = ((unsigned)out_ids[i]) >> shift;
        atomicOr(&filt[g >> 5], 1u << (g & 31));
    }
    __syncthreads();

    const int bytemode = *flag;
    const int lane = threadIdx.x & 63;
    const int wv = threadIdx.x >> 6;
    int2* wq = &lq[wv * QWCAP];
    int* mycnt = &wcnt[wv];

    int gtid = blockIdx.x * blockDim.x + threadIdx.x;
    int gstride = gridDim.x * blockDim.x;
    int nq = E >> 2;
    const v4i* d4p = (const v4i*)dst;

#define PROBE(dv, hv, k)                                                       \
    { unsigned dd = (unsigned)(dv) >> shift;                                   \
      hv |= ((filt[dd >> 5] >> (dd & 31)) & 1u) << (k); }

#define ENQ(ev, dv)                                                            \
    { int off = atomicAdd(mycnt, 1);                                           \
      if (off < QWCAP) wq[off] = make_int2((ev), (int)(dv));                   \
      else process_edge((int)(dv), (ev), w, src, rmb, input_idx,               \
                        state, inp, acc, bytemode); }

    for (int t = gtid; t < nq; t += 2 * gstride) {
        int tB = t + gstride;
        bool vB = tB < nq;
        v4i A = __builtin_nontemporal_load(d4p + t);
        v4i B = vB ? __builtin_nontemporal_load(d4p + tB) : (v4i)(0);

        unsigned mA = 0, mB = 0;
        PROBE(A.x, mA, 0) PROBE(A.y, mA, 1) PROBE(A.z, mA, 2) PROBE(A.w, mA, 3)
        PROBE(B.x, mB, 0) PROBE(B.y, mB, 1) PROBE(B.z, mB, 2) PROBE(B.w, mB, 3)
        if (!vB) mB = 0;

        if (mA | mB) {
            int ea = t << 2, eb = tB << 2;
            if (mA & 1) ENQ(ea + 0, A.x)
            if (mA & 2) ENQ(ea + 1, A.y)
            if (mA & 4) ENQ(ea + 2, A.z)
            if (mA & 8) ENQ(ea + 3, A.w)
            if (mB & 1) ENQ(eb + 0, B.x)
            if (mB & 2) ENQ(eb + 1, B.y)
            if (mB & 4) ENQ(eb + 2, B.z)
            if (mB & 8) ENQ(eb + 3, B.w)
        }

        // staggered per-wave drain: overlap random hit traffic with the
        // other waves' streaming (no barriers, wave-uniform condition)
        int have = *mycnt;
        if (have >= DRAIN_THRESH) {
            int nn = have < QWCAP ? have : QWCAP;
            for (int i = lane; i < nn; i += 64) {
                int2 c = wq[i];
                process_edge(c.y, c.x, w, src, rmb, input_idx,
                             state, inp, acc, bytemode);
            }
            if (lane == 0) *mycnt = 0;
        }
    }
#undef PROBE
#undef ENQ

    // tail edges (E not divisible by 4): process inline (true-dst adds)
    int rem = E - nq * 4;
    if (gtid < rem) {
        int e = nq * 4 + gtid;
        int d = dst[e];
        process_edge(d, e, w, src, rmb, input_idx, state, inp, acc, bytemode);
    }

    // final per-wave drain
    {
        int have = *mycnt;
        int nn = have < QWCAP ? have : QWCAP;
        for (int i = lane; i < nn; i += 64) {
            int2 c = wq[i];
            process_edge(c.y, c.x, w, src, rmb, input_idx,
                         state, inp, acc, bytemode);
        }
    }
}

// ---------------------------------------------------------------------------
// Kernel 3: activation + gather of the NOUT requested neurons.
// ---------------------------------------------------------------------------
__global__ void gather_out(const float* __restrict__ acc,
                           const int* __restrict__ act_id,
                           const int* __restrict__ out_ids,
                           float* __restrict__ out, int nout) {
    int i = blockIdx.x * blockDim.x + threadIdx.x;
    if (i >= nout) return;
    int n = out_ids[i];
    float x = acc[n];
    float y;
    switch (act_id[n]) {
        case 0: y = x; break;                                   // identity
        case 1: y = fmaxf(x, 0.0f); break;                      // relu
        case 2: y = x > 0.0f ? x : 0.01f * x; break;            // leaky_relu
        case 3: y = fminf(fmaxf(x, 0.0f), 1.0f); break;         // clipped_relu
        case 4: y = tanhf(x); break;                            // tanh
        case 5: y = 1.0f / (1.0f + expf(-x)); break;            // sigmoid
        case 6: y = fmaxf(x, 0.0f) + log1pf(expf(-fabsf(x))); break; // softplus
        default: y = fabsf(x); break;                           // abs
    }
    out[i] = y;
}

extern "C" void kernel_launch(void* const* d_in, const int* in_sizes, int n_in,
                              void* d_out, int out_size, void* d_ws, size_t ws_size,
                              hipStream_t stream) {
    const float* state     = (const float*)d_in[0];
    const float* weights   = (const float*)d_in[1];
    const float* biases    = (const float*)d_in[2];
    const float* inp       = (const float*)d_in[3];
    const int*   src       = (const int*)d_in[4];
    const int*   dst       = (const int*)d_in[5];
    const void*  rec_mask  = d_in[6];
    const int*   input_idx = (const int*)d_in[7];
    const int*   act_id    = (const int*)d_in[8];
    const int*   out_ids   = (const int*)d_in[9];
    float*       out       = (float*)d_out;

    const int N = in_sizes[0];
    const int E = in_sizes[1];
    const int NOUT = out_size;

    int*   flag = (int*)d_ws;
    float* acc  = (float*)((char*)d_ws + WS_ACC_OFF);

    // filter granularity: shift=0 (exact) when N fits 2^20 bits
    int shift = 0;
    while ((((long long)N + ((1LL << shift) - 1)) >> shift) > (long long)FILT_WORDS * 32)
        shift++;

    // 1) setup: detect rec_mask mode + init acc at out positions
    int nwords = E / 4;
    if (nwords > 2048) nwords = 2048;
    if (nwords < 1) nwords = 1;
    int setupBlocks = 1 + (NOUT + 255) / 256;
    setup<<<setupBlocks, 256, 0, stream>>>((const unsigned int*)rec_mask, nwords,
                                           flag, out_ids, state, biases, acc, NOUT);

    // 2) fused: in-block exact filter + nt stream + per-wave staggered drains
    edge_fused<<<256, 1024, 0, stream>>>(
        dst, out_ids, NOUT, E, shift,
        weights, src, (const unsigned char*)rec_mask, input_idx,
        state, inp, acc, flag);

    // 3) activation + gather
    gather_out<<<(NOUT + 255) / 256, 256, 0, stream>>>(acc, act_id, out_ids, out, NOUT);
}

// Round 17
// 37.666 us; speedup vs baseline: 1.1105x; 1.1105x over previous
//
#include <hip/hip_runtime.h>
#include <math.h>

#define REFRACTORY 0.33f
#define FILT_WORDS 32768     // 128 KB LDS bitmap: 1,048,576 bits (exact, N<=2^20)
#define QWCAP 128            // per-WAVE queue entries (int2) -> 16 KB total
#define NWAVES 16            // 1024 threads / 64
#define DRAIN_THRESH 16

// ws layout: [0,4) flag (rec_mask byte-mode); [256, 256+4*N) acc
#define WS_ACC_OFF 256

// ---------------------------------------------------------------------------
// Kernel 1 (setup): block 0 detects rec_mask storage mode (int32: dwords 0/1;
// packed bool bytes: dword view > 1); blocks 1.. init acc = 0.33*state + bias
// at output-neuron positions (the only acc slots ever read).
// ---------------------------------------------------------------------------
__global__ void setup(const unsigned int* __restrict__ rm, int nwords,
                      int* __restrict__ flag,
                      const int* __restrict__ out_ids,
                      const float* __restrict__ state,
                      const float* __restrict__ biases,
                      float* __restrict__ acc, int nout) {
    if (blockIdx.x == 0) {
        __shared__ int s;
        if (threadIdx.x == 0) s = 0;
        __syncthreads();
        int found = 0;
        for (int i = threadIdx.x; i < nwords; i += blockDim.x)
            if (rm[i] > 1u) found = 1;
        if (found) atomicOr(&s, 1);
        __syncthreads();
        if (threadIdx.x == 0) *flag = s;
    } else {
        int i = (blockIdx.x - 1) * blockDim.x + threadIdx.x;
        if (i < nout) {
            int n = out_ids[i];
            acc[n] = REFRACTORY * state[n] + biases[n];
        }
    }
}

// ---------------------------------------------------------------------------
// Full edge processing. Adds always land on the edge's TRUE dst; acc is only
// read at out_ids positions, so any extra add (shift>0 FPs) is invisible.
// ---------------------------------------------------------------------------
__device__ __forceinline__ void process_edge(
    int d, int e,
    const float* __restrict__ w, const int* __restrict__ src,
    const unsigned char* __restrict__ rmb, const int* __restrict__ input_idx,
    const float* __restrict__ state, const float* __restrict__ inp,
    float* __restrict__ acc, int bytemode) {
    int m = bytemode ? (int)rmb[e] : ((const int*)rmb)[e];
    float v = m ? REFRACTORY * state[src[e]] : inp[input_idx[e]];
    unsafeAtomicAdd(&acc[d], w[e] * v);
}

// ---------------------------------------------------------------------------
// Kernel 2 (fused): exact 128 KB LDS bitmap built in-block from out_ids.
// Stream dst with branch-free probes into PER-WAVE queues; drain own queue
// whenever it reaches DRAIN_THRESH (staggered across waves -> random drain
// traffic overlaps sequential stream traffic chip-wide). No barriers after
// the filter build. One block per CU.
// ---------------------------------------------------------------------------
__global__ void __launch_bounds__(1024, 1)
edge_fused(const int* __restrict__ dst,
           const int* __restrict__ out_ids, int nout,
           int E, int shift,
           const float* __restrict__ w, const int* __restrict__ src,
           const unsigned char* __restrict__ rmb,
           const int* __restrict__ input_idx,
           const float* __restrict__ state, const float* __restrict__ inp,
           float* __restrict__ acc,
           const int* __restrict__ flag) {
    __shared__ unsigned int filt[FILT_WORDS];
    __shared__ int2 lq[NWAVES * QWCAP];
    __shared__ int wcnt[NWAVES];

    // zero bitmap
    {
        uint4* f4 = (uint4*)filt;
        uint4 z = make_uint4(0, 0, 0, 0);
        for (int i = threadIdx.x; i < FILT_WORDS / 4; i += blockDim.x)
            f4[i] = z;
    }
    if ((threadIdx.x & 63) == 0) wcnt[threadIdx.x >> 6] = 0;
    __syncthreads();
    // build exact membership bitmap from out_ids (L2-hot broadcast read)
    for (int i = threadIdx.x; i < nout; i += blockDim.x) {
        unsigned g = ((unsigned)out_ids[i]) >> shift;
        atomicOr(&filt[g >> 5], 1u << (g & 31));
    }
    __syncthreads();

    const int bytemode = *flag;
    const int lane = threadIdx.x & 63;
    const int wv = threadIdx.x >> 6;
    int2* wq = &lq[wv * QWCAP];
    int* mycnt = &wcnt[wv];

    int gtid = blockIdx.x * blockDim.x + threadIdx.x;
    int gstride = gridDim.x * blockDim.x;
    int nq = E >> 2;
    const int4* d4p = (const int4*)dst;

#define PROBE(dv, hv, k)                                                       \
    { unsigned dd = (unsigned)(dv) >> shift;                                   \
      hv |= ((filt[dd >> 5] >> (dd & 31)) & 1u) << (k); }

#define ENQ(ev, dv)                                                            \
    { int off = atomicAdd(mycnt, 1);                                           \
      if (off < QWCAP) wq[off] = make_int2((ev), (int)(dv));                   \
      else process_edge((int)(dv), (ev), w, src, rmb, input_idx,               \
                        state, inp, acc, bytemode); }

    for (int t = gtid; t < nq; t += 2 * gstride) {
        int tB = t + gstride;
        bool vB = tB < nq;
        int4 A = d4p[t];
        int4 B = vB ? d4p[tB] : make_int4(0, 0, 0, 0);

        unsigned mA = 0, mB = 0;
        PROBE(A.x, mA, 0) PROBE(A.y, mA, 1) PROBE(A.z, mA, 2) PROBE(A.w, mA, 3)
        PROBE(B.x, mB, 0) PROBE(B.y, mB, 1) PROBE(B.z, mB, 2) PROBE(B.w, mB, 3)
        if (!vB) mB = 0;

        if (mA | mB) {
            int ea = t << 2, eb = tB << 2;
            if (mA & 1) ENQ(ea + 0, A.x)
            if (mA & 2) ENQ(ea + 1, A.y)
            if (mA & 4) ENQ(ea + 2, A.z)
            if (mA & 8) ENQ(ea + 3, A.w)
            if (mB & 1) ENQ(eb + 0, B.x)
            if (mB & 2) ENQ(eb + 1, B.y)
            if (mB & 4) ENQ(eb + 2, B.z)
            if (mB & 8) ENQ(eb + 3, B.w)
        }

        // staggered per-wave drain: overlap random hit traffic with the
        // other waves' streaming (no barriers, wave-uniform condition)
        int have = *mycnt;
        if (have >= DRAIN_THRESH) {
            int nn = have < QWCAP ? have : QWCAP;
            for (int i = lane; i < nn; i += 64) {
                int2 c = wq[i];
                process_edge(c.y, c.x, w, src, rmb, input_idx,
                             state, inp, acc, bytemode);
            }
            if (lane == 0) *mycnt = 0;
        }
    }
#undef PROBE
#undef ENQ

    // tail edges (E not divisible by 4): process inline (true-dst adds)
    int rem = E - nq * 4;
    if (gtid < rem) {
        int e = nq * 4 + gtid;
        int d = dst[e];
        process_edge(d, e, w, src, rmb, input_idx, state, inp, acc, bytemode);
    }

    // final per-wave drain
    {
        int have = *mycnt;
        int nn = have < QWCAP ? have : QWCAP;
        for (int i = lane; i < nn; i += 64) {
            int2 c = wq[i];
            process_edge(c.y, c.x, w, src, rmb, input_idx,
                         state, inp, acc, bytemode);
        }
    }
}

// ---------------------------------------------------------------------------
// Kernel 3: activation + gather of the NOUT requested neurons.
// ---------------------------------------------------------------------------
__global__ void gather_out(const float* __restrict__ acc,
                           const int* __restrict__ act_id,
                           const int* __restrict__ out_ids,
                           float* __restrict__ out, int nout) {
    int i = blockIdx.x * blockDim.x + threadIdx.x;
    if (i >= nout) return;
    int n = out_ids[i];
    float x = acc[n];
    float y;
    switch (act_id[n]) {
        case 0: y = x; break;                                   // identity
        case 1: y = fmaxf(x, 0.0f); break;                      // relu
        case 2: y = x > 0.0f ? x : 0.01f * x; break;            // leaky_relu
        case 3: y = fminf(fmaxf(x, 0.0f), 1.0f); break;         // clipped_relu
        case 4: y = tanhf(x); break;                            // tanh
        case 5: y = 1.0f / (1.0f + expf(-x)); break;            // sigmoid
        case 6: y = fmaxf(x, 0.0f) + log1pf(expf(-fabsf(x))); break; // softplus
        default: y = fabsf(x); break;                           // abs
    }
    out[i] = y;
}

extern "C" void kernel_launch(void* const* d_in, const int* in_sizes, int n_in,
                              void* d_out, int out_size, void* d_ws, size_t ws_size,
                              hipStream_t stream) {
    const float* state     = (const float*)d_in[0];
    const float* weights   = (const float*)d_in[1];
    const float* biases    = (const float*)d_in[2];
    const float* inp       = (const float*)d_in[3];
    const int*   src       = (const int*)d_in[4];
    const int*   dst       = (const int*)d_in[5];
    const void*  rec_mask  = d_in[6];
    const int*   input_idx = (const int*)d_in[7];
    const int*   act_id    = (const int*)d_in[8];
    const int*   out_ids   = (const int*)d_in[9];
    float*       out       = (float*)d_out;

    const int N = in_sizes[0];
    const int E = in_sizes[1];
    const int NOUT = out_size;

    int*   flag = (int*)d_ws;
    float* acc  = (float*)((char*)d_ws + WS_ACC_OFF);

    // filter granularity: shift=0 (exact) when N fits 2^20 bits
    int shift = 0;
    while ((((long long)N + ((1LL << shift) - 1)) >> shift) > (long long)FILT_WORDS * 32)
        shift++;

    // 1) setup: detect rec_mask mode + init acc at out positions
    int nwords = E / 4;
    if (nwords > 2048) nwords = 2048;
    if (nwords < 1) nwords = 1;
    int setupBlocks = 1 + (NOUT + 255) / 256;
    setup<<<setupBlocks, 256, 0, stream>>>((const unsigned int*)rec_mask, nwords,
                                           flag, out_ids, state, biases, acc, NOUT);

    // 2) fused: in-block exact filter + stream + per-wave staggered drains
    edge_fused<<<256, 1024, 0, stream>>>(
        dst, out_ids, NOUT, E, shift,
        weights, src, (const unsigned char*)rec_mask, input_idx,
        state, inp, acc, flag);

    // 3) activation + gather
    gather_out<<<(NOUT + 255) / 256, 256, 0, stream>>>(acc, act_id, out_ids, out, NOUT);
}